// Round 6
// baseline (193.771 us; speedup 1.0000x reference)
//
#include <hip/hip_runtime.h>
#include <math.h>

#define DIM 128
#define LN_EPS 1e-5f
#define TWO32 4294967296.0
#define INV32 (1.0 / 4294967296.0)

typedef __attribute__((ext_vector_type(8))) short short8;   // 8 bf16 = 4 VGPR
typedef __attribute__((ext_vector_type(4))) float floatx4;

__device__ __forceinline__ float gelu_exact(float v) {
    return 0.5f * v * (1.0f + erff(v * 0.70710678118654752f));
}
__device__ __forceinline__ float bf2f(unsigned short u) {
    return __uint_as_float(((unsigned)u) << 16);
}
__device__ __forceinline__ short f2bf(float f) {
    unsigned b = __float_as_uint(f);
    return (short)((b + 0x7FFF + ((b >> 16) & 1)) >> 16);  // RNE
}

// ---------------------------------------------------------------------------
// Fused: rank-role blocks (blockIdx%3==2) do ONE f64 atomic per edge into an
// 8-replica accumulator: acc8[r][c] += 2^32 + ew  (count in high bits, sum of
// edge weights in low). Returned old value -> replica-local rank. GEMM-role
// blocks: LN + h = xn@W^T via bf16 MFMA (fragment-order LDS, conflict-free).
// ---------------------------------------------------------------------------
__global__ __launch_bounds__(256) void gemm_rank_kernel(
    const float* __restrict__ x, const float* __restrict__ W,
    const float* __restrict__ lnw, const float* __restrict__ lnb,
    unsigned short* __restrict__ h16,
    const int* __restrict__ col, const float* __restrict__ ew,
    double* __restrict__ acc8, int* __restrict__ rnk,
    int n, int E)
{
    const int tid = threadIdx.x;

    if ((int)(blockIdx.x % 3) == 2) {
        // ------------- rank role: 1 f64 atomic per edge -------------
        int rb   = blockIdx.x / 3;
        int r    = rb & 7;                       // replica
        size_t rbase = (size_t)r * n;
        int base = rb * 2048 + tid;
        #pragma unroll
        for (int it = 0; it < 8; ++it) {
            int e = base + it * 256;
            if (e < E) {
                int c = col[e];
                double old = atomicAdd(&acc8[rbase + c], TWO32 + (double)ew[e]);
                int rk = (int)(old * INV32);     // floor: replica-local rank
                rnk[e] = (r << 24) | rk;
            }
        }
        return;
    }

    __shared__ short swb[2048 * 8];   // 32 KB: W bf16 fragments
    __shared__ short axb[1024 * 8];   // 16 KB: xn bf16 fragments

    const int gb = blockIdx.x - (blockIdx.x + 1) / 3;
    const int n0 = gb * 64;

    // ---- stage W fragments (fragment-order slots, conflict-free reads) ----
    for (int c = tid; c < 2048; c += 256) {
        int nrow = ((c >> 8) << 4) | (c & 15);                    // jt*16+nloc
        int kb   = (((c >> 6) & 3) << 5) + (((c >> 4) & 3) << 3); // kq*32+quad*8
        const float* wp = W + nrow * DIM + kb;
        float4 w0 = *(const float4*)wp;
        float4 w1 = *(const float4*)(wp + 4);
        short8 p;
        p[0] = f2bf(w0.x); p[1] = f2bf(w0.y); p[2] = f2bf(w0.z); p[3] = f2bf(w0.w);
        p[4] = f2bf(w1.x); p[5] = f2bf(w1.y); p[6] = f2bf(w1.z); p[7] = f2bf(w1.w);
        *(short8*)&swb[c * 8] = p;
    }

    // ---- LayerNorm straight from global (x read once), 4 threads/node ----
    {
        int m = tid >> 2, sub = tid & 3;
        int node = n0 + m;
        bool valid = (node < n);
        const float4* xp = (const float4*)(x + (size_t)node * DIM + sub * 32);
        float4 v[8];
        float s = 0.f, ss = 0.f;
        #pragma unroll
        for (int i = 0; i < 8; ++i) {
            v[i] = valid ? xp[i] : make_float4(0.f, 0.f, 0.f, 0.f);
            s  += v[i].x + v[i].y + v[i].z + v[i].w;
            ss += v[i].x * v[i].x + v[i].y * v[i].y + v[i].z * v[i].z + v[i].w * v[i].w;
        }
        s += __shfl_xor(s, 1); ss += __shfl_xor(ss, 1);
        s += __shfl_xor(s, 2); ss += __shfl_xor(ss, 2);
        float mu   = s * (1.0f / 128.0f);
        float var  = ss * (1.0f / 128.0f) - mu * mu;
        float rstd = rsqrtf(var + LN_EPS);

        int mt = m >> 4, mloc = m & 15;
        #pragma unroll
        for (int quad = 0; quad < 4; ++quad) {
            float4 a = v[2 * quad], c4 = v[2 * quad + 1];
            const float4* lw = (const float4*)(lnw + sub * 32 + quad * 8);
            const float4* lb = (const float4*)(lnb + sub * 32 + quad * 8);
            float4 lw0 = lw[0], lw1 = lw[1], lb0 = lb[0], lb1 = lb[1];
            short8 p;
            p[0] = f2bf((a.x  - mu) * rstd * lw0.x + lb0.x);
            p[1] = f2bf((a.y  - mu) * rstd * lw0.y + lb0.y);
            p[2] = f2bf((a.z  - mu) * rstd * lw0.z + lb0.z);
            p[3] = f2bf((a.w  - mu) * rstd * lw0.w + lb0.w);
            p[4] = f2bf((c4.x - mu) * rstd * lw1.x + lb1.x);
            p[5] = f2bf((c4.y - mu) * rstd * lw1.y + lb1.y);
            p[6] = f2bf((c4.z - mu) * rstd * lw1.z + lb1.z);
            p[7] = f2bf((c4.w - mu) * rstd * lw1.w + lb1.w);
            int slot = mt * 256 + sub * 64 + quad * 16 + mloc;
            *(short8*)&axb[slot * 8] = p;
        }
    }
    __syncthreads();

    // ---- MFMA compute: wave w -> m-tile w, all 8 j-tiles ----
    const int w    = tid >> 6;
    const int lane = tid & 63;

    short8 afrag[4];
    #pragma unroll
    for (int kq = 0; kq < 4; ++kq)
        afrag[kq] = *(const short8*)&axb[(w * 256 + kq * 64 + lane) * 8];

    floatx4 acc[8];
    #pragma unroll
    for (int jt = 0; jt < 8; ++jt) acc[jt] = (floatx4){0.f, 0.f, 0.f, 0.f};

    #pragma unroll
    for (int jt = 0; jt < 8; ++jt) {
        #pragma unroll
        for (int kq = 0; kq < 4; ++kq) {
            short8 bfrag = *(const short8*)&swb[(jt * 256 + kq * 64 + lane) * 8];
            acc[jt] = __builtin_amdgcn_mfma_f32_16x16x32_bf16(afrag[kq], bfrag,
                                                              acc[jt], 0, 0, 0);
        }
    }

    // ---- epilogue: D row = quad*4+reg, col = jt*16 + (lane&15) ----
    const int quad = lane >> 4, nl = lane & 15;
    #pragma unroll
    for (int jt = 0; jt < 8; ++jt) {
        #pragma unroll
        for (int r = 0; r < 4; ++r) {
            int rnode = n0 + w * 16 + quad * 4 + r;
            if (rnode < n)
                h16[(size_t)rnode * DIM + jt * 16 + nl] = (unsigned short)f2bf(acc[jt][r]);
        }
    }
}

// ---------------------------------------------------------------------------
// Scan A: per-1024-node chunk sums of total count (8 replicas folded)
// ---------------------------------------------------------------------------
__global__ __launch_bounds__(256) void scan_a_kernel(
    const double* __restrict__ acc8, int* __restrict__ bsum, int n)
{
    __shared__ int lds[256];
    int t = threadIdx.x, b = blockIdx.x;
    int base = b * 1024 + t * 4;
    int s = 0;
    #pragma unroll
    for (int i = 0; i < 4; ++i) {
        int c = base + i;
        if (c < n) {
            int k = 0;
            for (int r = 0; r < 8; ++r)
                k += (int)(acc8[(size_t)r * n + c] * INV32);
            s += k;
        }
    }
    lds[t] = s; __syncthreads();
    for (int off = 128; off > 0; off >>= 1) {
        if (t < off) lds[t] += lds[t + off];
        __syncthreads();
    }
    if (t == 0) bsum[b] = lds[0];
}

// ---------------------------------------------------------------------------
// Scan BC: fold bsum prefix + block-local exclusive scan; emit per-replica
// slot bases off8[r][c] = offsets[c] + sum_{q<r} k_q[c], and dinv[c].
// ---------------------------------------------------------------------------
__global__ __launch_bounds__(256) void scan_bc_kernel(
    const double* __restrict__ acc8, const int* __restrict__ bsum,
    int* __restrict__ off8, float* __restrict__ dinv, int nb, int n)
{
    __shared__ int lds[256];
    int t = threadIdx.x, b = blockIdx.x;
    int pre0 = 0, total = 0;
    for (int i = 0; i < nb; ++i) {
        int v = bsum[i];
        if (i < b) pre0 += v;
        total += v;
    }
    int base = b * 1024 + t * 4;

    int k8[4][8];
    int ksum[4];
    double wsum[4];
    #pragma unroll
    for (int i = 0; i < 4; ++i) {
        ksum[i] = 0; wsum[i] = 0.0;
        int c = base + i;
        if (c < n) {
            for (int r = 0; r < 8; ++r) {
                double v = acc8[(size_t)r * n + c];
                int k = (int)(v * INV32);
                k8[i][r] = k;
                ksum[i] += k;
                wsum[i] += v - (double)k * TWO32;
            }
        }
    }
    int s = ksum[0] + ksum[1] + ksum[2] + ksum[3];
    lds[t] = s; __syncthreads();
    int inc = s;
    for (int off = 1; off < 256; off <<= 1) {
        int add = (t >= off) ? lds[t - off] : 0;
        __syncthreads();
        inc += add;
        lds[t] = inc;
        __syncthreads();
    }
    int pre = pre0 + inc - s;  // exclusive prefix for this thread's 4 nodes
    #pragma unroll
    for (int i = 0; i < 4; ++i) {
        int c = base + i;
        if (c < n) {
            int run = pre;
            for (int r = 0; r < 8; ++r) {
                off8[(size_t)r * (n + 1) + c] = run;
                run += k8[i][r];
            }
            dinv[c] = rsqrtf(1.0f + (float)wsum[i]);
            pre = run;
        }
    }
    if (b == 0 && t == 0) off8[n] = total;  // offsets[n] = E (replica-0 row)
}

// ---------------------------------------------------------------------------
// Atomic-free fill: pos = off8[r][col] + rank; store (src, final nrm).
// ---------------------------------------------------------------------------
__global__ __launch_bounds__(256) void scatter_fill_kernel(
    const int* __restrict__ row, const int* __restrict__ col,
    const float* __restrict__ ew, const int* __restrict__ rnk,
    const int* __restrict__ off8, const float* __restrict__ dinv,
    int2* __restrict__ edge_s, int n, int E)
{
    int e = blockIdx.x * 256 + threadIdx.x;
    if (e < E) {
        int c  = col[e];
        int pk = rnk[e];
        int r  = pk >> 24;
        int rk = pk & 0xFFFFFF;
        int pos = off8[(size_t)r * (n + 1) + c] + rk;
        int src = row[e];
        float nr = dinv[src] * ew[e] * dinv[c];
        edge_s[pos] = make_int2(src, __float_as_int(nr));
    }
}

// ---------------------------------------------------------------------------
// Pull gather: 4 nodes/wave, 16 lanes x 8 dims, 16 B h16 loads; nrm is
// precomputed in edge_s. Fused self-loop + bias + exact GELU.
// ---------------------------------------------------------------------------
__global__ __launch_bounds__(256) void gather4_kernel(
    const int* __restrict__ offsets, const int2* __restrict__ edge_s,
    const float* __restrict__ dinv, const unsigned short* __restrict__ h16,
    const float* __restrict__ bias, float* __restrict__ out, int n)
{
    int wave = (blockIdx.x * 256 + threadIdx.x) >> 6;
    int lane = threadIdx.x & 63;
    int grp  = lane >> 4;
    int sub  = lane & 15;
    int node = wave * 4 + grp;
    if (node >= n) return;

    int beg = offsets[node], end = offsets[node + 1];
    float di = dinv[node];
    short8 sv = *(const short8*)(h16 + (size_t)node * DIM + sub * 8);
    float s2 = di * di;
    float acc[8];
    #pragma unroll
    for (int d = 0; d < 8; ++d) acc[d] = s2 * bf2f((unsigned short)sv[d]);

    int j = beg;
    for (; j + 3 < end; j += 4) {
        int2 e0 = edge_s[j],     e1 = edge_s[j + 1];
        int2 e2 = edge_s[j + 2], e3 = edge_s[j + 3];
        short8 a0 = *(const short8*)(h16 + (size_t)e0.x * DIM + sub * 8);
        short8 a1 = *(const short8*)(h16 + (size_t)e1.x * DIM + sub * 8);
        short8 a2 = *(const short8*)(h16 + (size_t)e2.x * DIM + sub * 8);
        short8 a3 = *(const short8*)(h16 + (size_t)e3.x * DIM + sub * 8);
        float n0 = __int_as_float(e0.y), n1 = __int_as_float(e1.y);
        float n2 = __int_as_float(e2.y), n3 = __int_as_float(e3.y);
        #pragma unroll
        for (int d = 0; d < 8; ++d) {
            acc[d] = fmaf(n0, bf2f((unsigned short)a0[d]), acc[d]);
            acc[d] = fmaf(n1, bf2f((unsigned short)a1[d]), acc[d]);
            acc[d] = fmaf(n2, bf2f((unsigned short)a2[d]), acc[d]);
            acc[d] = fmaf(n3, bf2f((unsigned short)a3[d]), acc[d]);
        }
    }
    for (; j < end; ++j) {
        int2 e0 = edge_s[j];
        float n0 = __int_as_float(e0.y);
        short8 a = *(const short8*)(h16 + (size_t)e0.x * DIM + sub * 8);
        #pragma unroll
        for (int d = 0; d < 8; ++d) acc[d] = fmaf(n0, bf2f((unsigned short)a[d]), acc[d]);
    }

    float4 b0 = *(const float4*)(bias + sub * 8);
    float4 b1 = *(const float4*)(bias + sub * 8 + 4);
    float4 o0, o1;
    o0.x = gelu_exact(acc[0] + b0.x); o0.y = gelu_exact(acc[1] + b0.y);
    o0.z = gelu_exact(acc[2] + b0.z); o0.w = gelu_exact(acc[3] + b0.w);
    o1.x = gelu_exact(acc[4] + b1.x); o1.y = gelu_exact(acc[5] + b1.y);
    o1.z = gelu_exact(acc[6] + b1.z); o1.w = gelu_exact(acc[7] + b1.w);
    float* op = out + (size_t)node * DIM + sub * 8;
    *(float4*)op       = o0;
    *(float4*)(op + 4) = o1;
}

extern "C" void kernel_launch(void* const* d_in, const int* in_sizes, int n_in,
                              void* d_out, int out_size, void* d_ws, size_t ws_size,
                              hipStream_t stream)
{
    const float* x    = (const float*)d_in[0];
    const int*   ei   = (const int*)d_in[1];
    const float* ew   = (const float*)d_in[2];
    const float* W    = (const float*)d_in[3];
    const float* b    = (const float*)d_in[4];
    const float* ln_w = (const float*)d_in[5];
    const float* ln_b = (const float*)d_in[6];
    float* out = (float*)d_out;

    const int n = in_sizes[0] / DIM;
    const int E = in_sizes[2];
    const int* row  = ei;        // sources
    const int* colp = ei + E;    // targets

    const int NB = (n + 1023) / 1024;

    // workspace layout (8B-aligned first)
    double*         acc8    = (double*)d_ws;                         // 8n f64
    int2*           edge_s  = (int2*)(acc8 + (size_t)8 * n);         // E int2
    unsigned short* h16     = (unsigned short*)(edge_s + E);         // n*128
    int*            rnk     = (int*)(h16 + (size_t)n * DIM);         // E
    int*            off8    = rnk + E;                               // 8(n+1)
    int*            bsum    = off8 + (size_t)8 * (n + 1);            // <=4096
    float*          dinv    = (float*)(bsum + 4096);                 // n
    // total ~27.5 MB (R2/R3 used ~39 MB successfully)

    const int GB = (n + 63) / 64;       // gemm blocks
    const int RB = (E + 2047) / 2048;   // rank blocks
    int T = GB + RB;
    while (T / 3 < RB || T - T / 3 < GB) ++T;

    hipMemsetAsync(acc8, 0, (size_t)8 * n * sizeof(double), stream);
    gemm_rank_kernel<<<T, 256, 0, stream>>>(x, W, ln_w, ln_b, h16,
                                            colp, ew, acc8, rnk, n, E);
    scan_a_kernel<<<NB, 256, 0, stream>>>(acc8, bsum, n);
    scan_bc_kernel<<<NB, 256, 0, stream>>>(acc8, bsum, off8, dinv, NB, n);
    scatter_fill_kernel<<<(E + 255) / 256, 256, 0, stream>>>(row, colp, ew, rnk,
                                                             off8, dinv, edge_s, n, E);
    {
        int waves  = (n + 3) / 4;
        int blocks = (waves + 3) / 4;
        gather4_kernel<<<blocks, 256, 0, stream>>>(off8, edge_s, dinv, h16, b, out, n);
    }
}